// Round 4
// baseline (423.989 us; speedup 1.0000x reference)
//
#include <hip/hip_runtime.h>
#include <hip/hip_bf16.h>
#include <math.h>

namespace {
constexpr int B_N = 4;
constexpr int T_N = 128;
constexpr int P_N = 256;
constexpr int D_N = 512;
constexpr int S_N = 64;
constexpr int NTH = 512;
constexpr int KC  = 64;

// LDS layout (bytes). Liveness (barrier-protected):
//   phase1 k-loop : XS [0,16384) + WS [16384,43008)
//   epilogue+scan : UB bf16 [0,16384) + BB bf16 [16384,32768) + CHB [32768,49152)
//   phase3        : ROS [0,16384) + CHB
constexpr int XS_OFF  = 0;
constexpr int WS_OFF  = 16384;
constexpr int UB_OFF  = 0;
constexpr int BB_OFF  = 16384;
constexpr int CH_OFF  = 32768;
constexpr int ROS_OFF = 0;
constexpr int DT_OFF  = 49152;
constexpr int LA_OFF  = 49664;
constexpr int LDS_BYTES = 49920;   // 3 blocks/CU (3x49920 = 146.3 KB < 160 KB)
}

typedef short bf16x8 __attribute__((ext_vector_type(8)));
typedef float f32x4  __attribute__((ext_vector_type(4)));

__device__ __forceinline__ unsigned short f2b(float f) {
    unsigned int x = __float_as_uint(f);
    return (unsigned short)((x + 0x7FFFu + ((x >> 16) & 1u)) >> 16);  // RNE
}
__device__ __forceinline__ float b2f(unsigned short h) {
    return __uint_as_float(((unsigned int)h) << 16);
}
// packed f32x2 -> bf16x2 (compiler emits v_cvt_pk_bf16_f32)
__device__ __forceinline__ unsigned int pk2(float lo, float hi) {
    union { __hip_bfloat162 h; unsigned int u; } cv;
    cv.h = __float22bfloat162_rn(float2{lo, hi});
    return cv.u;
}
// XOR-swizzled element index into a [rows][64] bf16 tile
__device__ __forceinline__ int swz(int row, int col) {
    return row * 64 + (col ^ ((row & 7) << 3));
}
// convert 8 f32 -> bf16x8, store as one b128
__device__ __forceinline__ void cvtstore8(unsigned short* dst, float4 a, float4 b) {
    uint4 r;
    r.x = pk2(a.x, a.y); r.y = pk2(a.z, a.w);
    r.z = pk2(b.x, b.y); r.w = pk2(b.z, b.w);
    *(uint4*)dst = r;
}
// stage 16 contiguous f32 as bf16 into swizzled tile
__device__ __forceinline__ void stage16(unsigned short* tile, int row, int col0,
                                        const float* __restrict__ src) {
    float4 v0 = *(const float4*)(src);
    float4 v1 = *(const float4*)(src + 4);
    float4 v2 = *(const float4*)(src + 8);
    float4 v3 = *(const float4*)(src + 12);
    cvtstore8(&tile[swz(row, col0)],     v0, v1);
    cvtstore8(&tile[swz(row, col0 + 8)], v2, v3);
}

__global__ __launch_bounds__(NTH, 6) void mamba_mfma(
    const float* __restrict__ X, const float* __restrict__ H0,
    const float* __restrict__ a_hat,
    const float* __restrict__ U_w, const float* __restrict__ sB_w, const float* __restrict__ sB_b,
    const float* __restrict__ sC_w, const float* __restrict__ sC_b,
    const float* __restrict__ sD1_w, const float* __restrict__ sD1_b,
    const float* __restrict__ sD2_w, const float* __restrict__ sD2_b,
    const float* __restrict__ ro_w,
    float* __restrict__ Hseq, float* __restrict__ Y, float* __restrict__ HT)
{
    __shared__ __align__(16) char smem[LDS_BYTES];
    unsigned short* XS  = (unsigned short*)(smem + XS_OFF);
    unsigned short* WS  = (unsigned short*)(smem + WS_OFF);
    unsigned short* UB  = (unsigned short*)(smem + UB_OFF);
    unsigned short* BB  = (unsigned short*)(smem + BB_OFF);
    unsigned short* ROS = (unsigned short*)(smem + ROS_OFF);
    unsigned short* CHB = (unsigned short*)(smem + CH_OFF);
    float*          DTB = (float*)(smem + DT_OFF);
    float*          LA  = (float*)(smem + LA_OFF);

    const int tid  = threadIdx.x;
    const int lane = tid & 63;
    const int wid  = tid >> 6;
    const int wm   = wid >> 2;     // 0..1
    const int wn   = wid & 3;      // 0..3
    const int l15  = lane & 15;
    const int lg   = lane >> 4;    // 0..3
    const int b    = blockIdx.x >> 8;
    const int p    = blockIdx.x & 255;

    if (tid < S_N) LA[tid] = -expf(a_hat[tid]);
    // zero WS rows 200..207 (dt B-frag garbage cols; read as zeros by dt MFMA)
    if (tid < 256) ((unsigned int*)(WS + 200 * 64))[tid] = 0;

    // ---------------- Phase 1: projection GEMM, M=128(t) N=192(+dt) K=512(d) ----------------
    f32x4 acc[4][3];
    f32x4 accdt[4];
    #pragma unroll
    for (int mf = 0; mf < 4; ++mf) {
        #pragma unroll
        for (int q = 0; q < 4; ++q) accdt[mf][q] = 0.0f;
        #pragma unroll
        for (int nf = 0; nf < 3; ++nf)
            #pragma unroll
            for (int q = 0; q < 4; ++q) acc[mf][nf][q] = 0.0f;
    }

    const int xr = tid >> 2;   // 0..127 (t row)
    const int xq = tid & 3;    // 0..3   (16-float quad)
    const float* xbase = X + (((size_t)b * T_N + xr) * P_N + p) * D_N + xq * 16;

    // prologue: prefetch chunk 0 of X into registers
    float4 xa = *(const float4*)(xbase);
    float4 xb = *(const float4*)(xbase + 4);
    float4 xc = *(const float4*)(xbase + 8);
    float4 xd = *(const float4*)(xbase + 12);

    for (int kc = 0; kc < D_N / KC; ++kc) {
        // write prefetched X regs to LDS
        cvtstore8(&XS[swz(xr, xq * 16)],     xa, xb);
        cvtstore8(&XS[swz(xr, xq * 16 + 8)], xc, xd);
        // stage weights (L2-resident after first blocks)
        for (int idx = tid; idx < 800; idx += NTH) {   // 200 rows x 4 quads
            int row = idx >> 2, kq = idx & 3;
            const float* wsrc;
            if (row < 64)       wsrc = U_w   + (size_t)row * D_N;
            else if (row < 128) wsrc = sB_w  + (size_t)(row - 64) * D_N;
            else if (row < 192) wsrc = sC_w  + (size_t)(row - 128) * D_N;
            else                wsrc = sD1_w + (size_t)(row - 192) * D_N;
            stage16(WS, row, kq * 16, wsrc + kc * KC + kq * 16);
        }
        __syncthreads();
        // issue next-chunk X loads BEFORE the MFMA cluster (latency hides under MFMA+barrier)
        if (kc + 1 < D_N / KC) {
            const float* nx = xbase + (kc + 1) * KC;
            xa = *(const float4*)(nx);
            xb = *(const float4*)(nx + 4);
            xc = *(const float4*)(nx + 8);
            xd = *(const float4*)(nx + 12);
        }
        #pragma unroll
        for (int kf = 0; kf < 2; ++kf) {
            const int kb = kf * 32 + lg * 8;   // consistent A/B k-permutation
            bf16x8 a[4];
            #pragma unroll
            for (int mf = 0; mf < 4; ++mf)
                a[mf] = *(const bf16x8*)&XS[swz(wm * 64 + mf * 16 + l15, kb)];
            #pragma unroll
            for (int nf = 0; nf < 3; ++nf) {
                bf16x8 bb = *(const bf16x8*)&WS[swz(wn * 48 + nf * 16 + l15, kb)];
                #pragma unroll
                for (int mf = 0; mf < 4; ++mf)
                    acc[mf][nf] = __builtin_amdgcn_mfma_f32_16x16x32_bf16(a[mf], bb, acc[mf][nf], 0, 0, 0);
            }
            if (wn == 0) {   // dt-feat extra N-frag (cols 0..7 valid, 8..15 zeros)
                bf16x8 bd = *(const bf16x8*)&WS[swz(192 + l15, kb)];
                #pragma unroll
                for (int mf = 0; mf < 4; ++mf)
                    accdt[mf] = __builtin_amdgcn_mfma_f32_16x16x32_bf16(a[mf], bd, accdt[mf], 0, 0, 0);
            }
        }
        __syncthreads();
    }

    // ---------------- Phase 1 epilogue: scatter u/B/C fragments, dt reduce ----------------
    // C/D frag layout (m89-verified): col = lane&15, row = (lane>>4)*4 + reg
    #pragma unroll
    for (int nf = 0; nf < 3; ++nf) {
        const int abscol = wn * 48 + nf * 16 + l15;
        const int kind = abscol >> 6;        // 0=u 1=B 2=C  (uniform per (wn,nf))
        const int s = abscol & 63;
        const float bias = (kind == 0) ? 0.0f : (kind == 1 ? sB_b[s] : sC_b[s]);
        #pragma unroll
        for (int mf = 0; mf < 4; ++mf) {
            #pragma unroll
            for (int q = 0; q < 4; ++q) {
                const int t = wm * 64 + mf * 16 + lg * 4 + q;
                const float v = acc[mf][nf][q] + bias;
                if (kind == 0)      UB[t * 64 + s] = f2b(v);      // u (bf16)
                else if (kind == 1) BB[t * 64 + s] = f2b(v);      // B+bias (bf16)
                else                CHB[swz(t, s)] = f2b(v);      // C+bias (bf16)
            }
        }
    }
    if (wn == 0) {
        const float w2 = (l15 < 8) ? sD2_w[l15] : 0.0f;
        const float b1 = (l15 < 8) ? sD1_b[l15] : 0.0f;
        const float b2 = sD2_b[0];
        #pragma unroll
        for (int mf = 0; mf < 4; ++mf) {
            #pragma unroll
            for (int q = 0; q < 4; ++q) {
                float z = accdt[mf][q] + b1;
                float w = (z / (1.0f + expf(-z))) * w2;   // silu * sD2_w
                w = (l15 < 8) ? w : 0.0f;
                w += __shfl_xor(w, 1);
                w += __shfl_xor(w, 2);
                w += __shfl_xor(w, 4);
                if (l15 == 0) {
                    float zz = w + b2;
                    DTB[wm * 64 + mf * 16 + lg * 4 + q] = (zz > 20.0f) ? zz : log1pf(expf(zz));
                }
            }
        }
    }
    __syncthreads();

    // ---------------- Phase 2: sequential scan (reference clamp semantics, fp32) ----------------
    if (tid < 64) {
        const int s = tid;
        const float la = LA[s];
        const float h0 = H0[((size_t)b * P_N + p) * S_N + s];
        float Pcv = 1.0f, cv = 0.0f, Hv = 0.0f;
        float* hout = Hseq + ((size_t)b * T_N * P_N + p) * S_N + s;
        for (int t = 0; t < T_N; ++t) {
            const float Av = expf(DTB[t] * la);
            const float bv = (1.0f - Av) * (b2f(BB[t * 64 + s]) * b2f(UB[t * 64 + s]));
            Pcv *= fmaxf(Av, 1e-12f);                 // Pc = cumprod(max(A,eps))
            cv += bv * (1.0f / fmaxf(Pcv, 1e-12f));   // c += b * invP (reference rounding order)
            Hv = Pcv * (h0 + cv);
            hout[(size_t)t * P_N * S_N] = Hv;
            const int e = swz(t, s);
            CHB[e] = f2b(b2f(CHB[e]) * Hv);           // CH = C * H (bf16)
        }
        HT[((size_t)b * P_N + p) * S_N + s] = Hv;
    }
    __syncthreads();

    // ---------------- Phase 3: Y = CH(128x64) x ro^T(64x512), four 128-wide passes ----------------
    for (int pp = 0; pp < 4; ++pp) {
        {   // stage ro rows [pp*128, pp*128+128): 128 rows x 4 quads = 512 units, 1/thread
            const int row = tid >> 2, kq = tid & 3;
            stage16(ROS, row, kq * 16, ro_w + ((size_t)(pp * 128 + row)) * S_N + kq * 16);
        }
        __syncthreads();
        f32x4 yacc[4][2];
        #pragma unroll
        for (int mf = 0; mf < 4; ++mf)
            #pragma unroll
            for (int nf = 0; nf < 2; ++nf)
                #pragma unroll
                for (int q = 0; q < 4; ++q) yacc[mf][nf][q] = 0.0f;
        #pragma unroll
        for (int kf = 0; kf < 2; ++kf) {
            const int kb = kf * 32 + lg * 8;
            bf16x8 a[4];
            #pragma unroll
            for (int mf = 0; mf < 4; ++mf)
                a[mf] = *(const bf16x8*)&CHB[swz(wm * 64 + mf * 16 + l15, kb)];
            #pragma unroll
            for (int nf = 0; nf < 2; ++nf) {
                bf16x8 bb = *(const bf16x8*)&ROS[swz(wn * 32 + nf * 16 + l15, kb)];
                #pragma unroll
                for (int mf = 0; mf < 4; ++mf)
                    yacc[mf][nf] = __builtin_amdgcn_mfma_f32_16x16x32_bf16(a[mf], bb, yacc[mf][nf], 0, 0, 0);
            }
        }
        #pragma unroll
        for (int mf = 0; mf < 4; ++mf) {
            const int t0 = wm * 64 + mf * 16 + lg * 4;
            float* ybase = Y + (((size_t)b * T_N + t0) * P_N + p) * D_N + pp * 128 + wn * 32 + l15;
            #pragma unroll
            for (int nf = 0; nf < 2; ++nf) {
                #pragma unroll
                for (int q = 0; q < 4; ++q)
                    ybase[(size_t)q * P_N * D_N + nf * 16] = yacc[mf][nf][q];
            }
        }
        if (pp < 3) __syncthreads();
    }
}

extern "C" void kernel_launch(void* const* d_in, const int* in_sizes, int n_in,
                              void* d_out, int out_size, void* d_ws, size_t ws_size,
                              hipStream_t stream) {
    const float* X     = (const float*)d_in[0];
    const float* H0    = (const float*)d_in[1];
    const float* a_hat = (const float*)d_in[2];
    const float* U_w   = (const float*)d_in[3];
    const float* sB_w  = (const float*)d_in[4];
    const float* sB_b  = (const float*)d_in[5];
    const float* sC_w  = (const float*)d_in[6];
    const float* sC_b  = (const float*)d_in[7];
    const float* sD1_w = (const float*)d_in[8];
    const float* sD1_b = (const float*)d_in[9];
    const float* sD2_w = (const float*)d_in[10];
    const float* sD2_b = (const float*)d_in[11];
    const float* ro_w  = (const float*)d_in[12];

    float* out   = (float*)d_out;
    float* HseqP = out;
    float* YP    = out + (size_t)B_N * T_N * P_N * S_N;
    float* HTP   = YP  + (size_t)B_N * T_N * P_N * D_N;

    hipLaunchKernelGGL(mamba_mfma, dim3(B_N * P_N), dim3(NTH), 0, stream,
                       X, H0, a_hat, U_w, sB_w, sB_b, sC_w, sC_b,
                       sD1_w, sD1_b, sD2_w, sD2_b, ro_w, HseqP, YP, HTP);
}

// Round 5
// 175.458 us; speedup vs baseline: 2.4165x; 2.4165x over previous
//
#include <hip/hip_runtime.h>
#include <hip/hip_bf16.h>
#include <math.h>

namespace {
constexpr int B_N = 4;
constexpr int T_N = 128;
constexpr int P_N = 256;
constexpr int D_N = 512;
constexpr int S_N = 64;
constexpr int NTH = 512;
constexpr int KC  = 64;

// LDS layout (bytes). Liveness (barrier-protected):
//   phase1 k-loop : XS [0,16384) + WS [16384,43008)
//   epilogue+scan : UB bf16 [0,16384) + BB bf16 [16384,32768) + CHB [32768,49152)
//   phase3        : ROS [0,32768) (UB+BB dead) + CHB
constexpr int XS_OFF  = 0;
constexpr int WS_OFF  = 16384;
constexpr int UB_OFF  = 0;
constexpr int BB_OFF  = 16384;
constexpr int CH_OFF  = 32768;
constexpr int ROS_OFF = 0;
constexpr int DT_OFF  = 49152;
constexpr int LA_OFF  = 49664;
constexpr int LDS_BYTES = 49920;   // 3 blocks/CU LDS-wise (149.8 KB < 160 KB)
}

typedef short bf16x8 __attribute__((ext_vector_type(8)));
typedef float f32x4  __attribute__((ext_vector_type(4)));

__device__ __forceinline__ unsigned short f2b(float f) {
    unsigned int x = __float_as_uint(f);
    return (unsigned short)((x + 0x7FFFu + ((x >> 16) & 1u)) >> 16);  // RNE
}
__device__ __forceinline__ float b2f(unsigned short h) {
    return __uint_as_float(((unsigned int)h) << 16);
}
// packed f32x2 -> bf16x2 (compiler emits v_cvt_pk_bf16_f32)
__device__ __forceinline__ unsigned int pk2(float lo, float hi) {
    union { __hip_bfloat162 h; unsigned int u; } cv;
    cv.h = __float22bfloat162_rn(float2{lo, hi});
    return cv.u;
}
// XOR-swizzled element index into a [rows][64] bf16 tile
__device__ __forceinline__ int swz(int row, int col) {
    return row * 64 + (col ^ ((row & 7) << 3));
}
// convert 8 f32 -> bf16x8, store as one b128
__device__ __forceinline__ void cvtstore8(unsigned short* dst, float4 a, float4 b) {
    uint4 r;
    r.x = pk2(a.x, a.y); r.y = pk2(a.z, a.w);
    r.z = pk2(b.x, b.y); r.w = pk2(b.z, b.w);
    *(uint4*)dst = r;
}
// stage 16 contiguous f32 as bf16 into swizzled tile
__device__ __forceinline__ void stage16(unsigned short* tile, int row, int col0,
                                        const float* __restrict__ src) {
    float4 v0 = *(const float4*)(src);
    float4 v1 = *(const float4*)(src + 4);
    float4 v2 = *(const float4*)(src + 8);
    float4 v3 = *(const float4*)(src + 12);
    cvtstore8(&tile[swz(row, col0)],     v0, v1);
    cvtstore8(&tile[swz(row, col0 + 8)], v2, v3);
}

__global__ __launch_bounds__(NTH, 4) void mamba_mfma(
    const float* __restrict__ X, const float* __restrict__ H0,
    const float* __restrict__ a_hat,
    const float* __restrict__ U_w, const float* __restrict__ sB_w, const float* __restrict__ sB_b,
    const float* __restrict__ sC_w, const float* __restrict__ sC_b,
    const float* __restrict__ sD1_w, const float* __restrict__ sD1_b,
    const float* __restrict__ sD2_w, const float* __restrict__ sD2_b,
    const float* __restrict__ ro_w,
    float* __restrict__ Hseq, float* __restrict__ Y, float* __restrict__ HT)
{
    __shared__ __align__(16) char smem[LDS_BYTES];
    unsigned short* XS  = (unsigned short*)(smem + XS_OFF);
    unsigned short* WS  = (unsigned short*)(smem + WS_OFF);
    unsigned short* UB  = (unsigned short*)(smem + UB_OFF);
    unsigned short* BB  = (unsigned short*)(smem + BB_OFF);
    unsigned short* ROS = (unsigned short*)(smem + ROS_OFF);
    unsigned short* CHB = (unsigned short*)(smem + CH_OFF);
    float*          DTB = (float*)(smem + DT_OFF);
    float*          LA  = (float*)(smem + LA_OFF);

    const int tid  = threadIdx.x;
    const int lane = tid & 63;
    const int wid  = tid >> 6;
    const int wm   = wid >> 2;     // 0..1
    const int wn   = wid & 3;      // 0..3
    const int l15  = lane & 15;
    const int lg   = lane >> 4;    // 0..3
    const int b    = blockIdx.x >> 8;
    const int p    = blockIdx.x & 255;

    if (tid < S_N) LA[tid] = -expf(a_hat[tid]);
    // zero WS rows 200..207 (dt B-frag garbage cols; read as zeros by dt MFMA)
    if (tid < 256) ((unsigned int*)(WS + 200 * 64))[tid] = 0;

    // ---------------- Phase 1: projection GEMM, M=128(t) N=192(+dt) K=512(d) ----------------
    f32x4 acc[4][3];
    f32x4 accdt[4];
    #pragma unroll
    for (int mf = 0; mf < 4; ++mf) {
        #pragma unroll
        for (int q = 0; q < 4; ++q) accdt[mf][q] = 0.0f;
        #pragma unroll
        for (int nf = 0; nf < 3; ++nf)
            #pragma unroll
            for (int q = 0; q < 4; ++q) acc[mf][nf][q] = 0.0f;
    }

    const int xr = tid >> 2;   // 0..127 (t row)
    const int xq = tid & 3;    // 0..3   (16-float quad)
    const float* xbase = X + (((size_t)b * T_N + xr) * P_N + p) * D_N + xq * 16;

    // prologue: prefetch chunk 0 of X into registers
    float4 xa = *(const float4*)(xbase);
    float4 xb = *(const float4*)(xbase + 4);
    float4 xc = *(const float4*)(xbase + 8);
    float4 xd = *(const float4*)(xbase + 12);

    for (int kc = 0; kc < D_N / KC; ++kc) {
        // write prefetched X regs to LDS
        cvtstore8(&XS[swz(xr, xq * 16)],     xa, xb);
        cvtstore8(&XS[swz(xr, xq * 16 + 8)], xc, xd);
        // stage weights (L2-resident after first use)
        for (int idx = tid; idx < 800; idx += NTH) {   // 200 rows x 4 quads
            int row = idx >> 2, kq = idx & 3;
            const float* wsrc;
            if (row < 64)       wsrc = U_w   + (size_t)row * D_N;
            else if (row < 128) wsrc = sB_w  + (size_t)(row - 64) * D_N;
            else if (row < 192) wsrc = sC_w  + (size_t)(row - 128) * D_N;
            else                wsrc = sD1_w + (size_t)(row - 192) * D_N;
            stage16(WS, row, kq * 16, wsrc + kc * KC + kq * 16);
        }
        __syncthreads();
        // issue next-chunk X loads BEFORE the MFMA cluster (latency hides under MFMA+barrier)
        if (kc + 1 < D_N / KC) {
            const float* nx = xbase + (kc + 1) * KC;
            xa = *(const float4*)(nx);
            xb = *(const float4*)(nx + 4);
            xc = *(const float4*)(nx + 8);
            xd = *(const float4*)(nx + 12);
        }
        #pragma unroll
        for (int kf = 0; kf < 2; ++kf) {
            const int kb = kf * 32 + lg * 8;   // consistent A/B k-permutation
            bf16x8 a[4];
            #pragma unroll
            for (int mf = 0; mf < 4; ++mf)
                a[mf] = *(const bf16x8*)&XS[swz(wm * 64 + mf * 16 + l15, kb)];
            #pragma unroll
            for (int nf = 0; nf < 3; ++nf) {
                bf16x8 bb = *(const bf16x8*)&WS[swz(wn * 48 + nf * 16 + l15, kb)];
                #pragma unroll
                for (int mf = 0; mf < 4; ++mf)
                    acc[mf][nf] = __builtin_amdgcn_mfma_f32_16x16x32_bf16(a[mf], bb, acc[mf][nf], 0, 0, 0);
            }
            if (wn == 0) {   // dt-feat extra N-frag (cols 0..7 valid, 8..15 zeros)
                bf16x8 bd = *(const bf16x8*)&WS[swz(192 + l15, kb)];
                #pragma unroll
                for (int mf = 0; mf < 4; ++mf)
                    accdt[mf] = __builtin_amdgcn_mfma_f32_16x16x32_bf16(a[mf], bd, accdt[mf], 0, 0, 0);
            }
        }
        __syncthreads();
    }

    // ---------------- Phase 1 epilogue: scatter u/B/C fragments, dt reduce ----------------
    // C/D frag layout (m89-verified): col = lane&15, row = (lane>>4)*4 + reg
    #pragma unroll
    for (int nf = 0; nf < 3; ++nf) {
        const int abscol = wn * 48 + nf * 16 + l15;
        const int kind = abscol >> 6;        // 0=u 1=B 2=C  (uniform per (wn,nf))
        const int s = abscol & 63;
        const float bias = (kind == 0) ? 0.0f : (kind == 1 ? sB_b[s] : sC_b[s]);
        #pragma unroll
        for (int mf = 0; mf < 4; ++mf) {
            #pragma unroll
            for (int q = 0; q < 4; ++q) {
                const int t = wm * 64 + mf * 16 + lg * 4 + q;
                const float v = acc[mf][nf][q] + bias;
                if (kind == 0)      UB[t * 64 + s] = f2b(v);      // u (bf16)
                else if (kind == 1) BB[t * 64 + s] = f2b(v);      // B+bias (bf16)
                else                CHB[swz(t, s)] = f2b(v);      // C+bias (bf16)
            }
        }
    }
    if (wn == 0) {
        const float w2 = (l15 < 8) ? sD2_w[l15] : 0.0f;
        const float b1 = (l15 < 8) ? sD1_b[l15] : 0.0f;
        const float b2 = sD2_b[0];
        #pragma unroll
        for (int mf = 0; mf < 4; ++mf) {
            #pragma unroll
            for (int q = 0; q < 4; ++q) {
                float z = accdt[mf][q] + b1;
                float w = (z / (1.0f + expf(-z))) * w2;   // silu * sD2_w
                w = (l15 < 8) ? w : 0.0f;
                w += __shfl_xor(w, 1);
                w += __shfl_xor(w, 2);
                w += __shfl_xor(w, 4);
                if (l15 == 0) {
                    float zz = w + b2;
                    DTB[wm * 64 + mf * 16 + lg * 4 + q] = (zz > 20.0f) ? zz : log1pf(expf(zz));
                }
            }
        }
    }
    __syncthreads();

    // ---------------- Phase 2: sequential scan (reference clamp semantics, fp32) ----------------
    if (tid < 64) {
        const int s = tid;
        const float la = LA[s];
        const float h0 = H0[((size_t)b * P_N + p) * S_N + s];
        float Pcv = 1.0f, cv = 0.0f, Hv = 0.0f;
        float* hout = Hseq + ((size_t)b * T_N * P_N + p) * S_N + s;
        for (int t = 0; t < T_N; ++t) {
            const float Av = expf(DTB[t] * la);
            const float bv = (1.0f - Av) * (b2f(BB[t * 64 + s]) * b2f(UB[t * 64 + s]));
            Pcv *= fmaxf(Av, 1e-12f);                 // Pc = cumprod(max(A,eps))
            cv += bv * (1.0f / fmaxf(Pcv, 1e-12f));   // c += b * invP (reference rounding order)
            Hv = Pcv * (h0 + cv);
            hout[(size_t)t * P_N * S_N] = Hv;
            const int e = swz(t, s);
            CHB[e] = f2b(b2f(CHB[e]) * Hv);           // CH = C * H (bf16)
        }
        HT[((size_t)b * P_N + p) * S_N + s] = Hv;
    }
    __syncthreads();

    // ---------------- Phase 3: Y = CH(128x64) x ro^T(64x512), two 256-wide passes ----------------
    for (int pp = 0; pp < 2; ++pp) {
        #pragma unroll
        for (int i = 0; i < 2; ++i) {                 // 256 rows x 4 quads = 1024 units
            const int idx = i * 512 + tid;
            const int row = idx >> 2, kq = idx & 3;
            stage16(ROS, row, kq * 16, ro_w + ((size_t)(pp * 256 + row)) * S_N + kq * 16);
        }
        __syncthreads();
        f32x4 yacc[4][4];
        #pragma unroll
        for (int mf = 0; mf < 4; ++mf)
            #pragma unroll
            for (int nf = 0; nf < 4; ++nf)
                #pragma unroll
                for (int q = 0; q < 4; ++q) yacc[mf][nf][q] = 0.0f;
        #pragma unroll
        for (int kf = 0; kf < 2; ++kf) {
            const int kb = kf * 32 + lg * 8;
            bf16x8 a[4];
            #pragma unroll
            for (int mf = 0; mf < 4; ++mf)
                a[mf] = *(const bf16x8*)&CHB[swz(wm * 64 + mf * 16 + l15, kb)];
            #pragma unroll
            for (int nf = 0; nf < 4; ++nf) {
                bf16x8 bb = *(const bf16x8*)&ROS[swz(wn * 64 + nf * 16 + l15, kb)];
                #pragma unroll
                for (int mf = 0; mf < 4; ++mf)
                    yacc[mf][nf] = __builtin_amdgcn_mfma_f32_16x16x32_bf16(a[mf], bb, yacc[mf][nf], 0, 0, 0);
            }
        }
        #pragma unroll
        for (int mf = 0; mf < 4; ++mf) {
            const int t0 = wm * 64 + mf * 16 + lg * 4;
            float* ybase = Y + (((size_t)b * T_N + t0) * P_N + p) * D_N + pp * 256 + wn * 64 + l15;
            #pragma unroll
            for (int nf = 0; nf < 4; ++nf) {
                #pragma unroll
                for (int q = 0; q < 4; ++q)
                    ybase[(size_t)q * P_N * D_N + nf * 16] = yacc[mf][nf][q];
            }
        }
        if (pp == 0) __syncthreads();
    }
}

extern "C" void kernel_launch(void* const* d_in, const int* in_sizes, int n_in,
                              void* d_out, int out_size, void* d_ws, size_t ws_size,
                              hipStream_t stream) {
    const float* X     = (const float*)d_in[0];
    const float* H0    = (const float*)d_in[1];
    const float* a_hat = (const float*)d_in[2];
    const float* U_w   = (const float*)d_in[3];
    const float* sB_w  = (const float*)d_in[4];
    const float* sB_b  = (const float*)d_in[5];
    const float* sC_w  = (const float*)d_in[6];
    const float* sC_b  = (const float*)d_in[7];
    const float* sD1_w = (const float*)d_in[8];
    const float* sD1_b = (const float*)d_in[9];
    const float* sD2_w = (const float*)d_in[10];
    const float* sD2_b = (const float*)d_in[11];
    const float* ro_w  = (const float*)d_in[12];

    float* out   = (float*)d_out;
    float* HseqP = out;
    float* YP    = out + (size_t)B_N * T_N * P_N * S_N;
    float* HTP   = YP  + (size_t)B_N * T_N * P_N * D_N;

    hipLaunchKernelGGL(mamba_mfma, dim3(B_N * P_N), dim3(NTH), 0, stream,
                       X, H0, a_hat, U_w, sB_w, sB_b, sC_w, sC_b,
                       sD1_w, sD1_b, sD2_w, sD2_b, ro_w, HseqP, YP, HTP);
}

// Round 6
// 159.617 us; speedup vs baseline: 2.6563x; 1.0992x over previous
//
#include <hip/hip_runtime.h>
#include <hip/hip_bf16.h>
#include <math.h>

namespace {
constexpr int B_N = 4, T_N = 128, P_N = 256, D_N = 512, S_N = 64;
constexpr int NTH = 512;
constexpr int KC  = 32;
constexpr int NCH = D_N / KC;   // 16 k-chunks

// LDS layout (bytes). Liveness (barrier-protected):
//   phase1 k-loop : XS [0,8192) + WS [8192,21504)
//   epilogue+scan : BU [0,16384) + CHB [16384,32768)
//   phase3        : ROS [0,16384) (BU dead) + CHB
constexpr int XS_OFF  = 0;       // bf16 [128][32] swz32
constexpr int WS_OFF  = 8192;    // bf16 [208][32] swz32 (rows 200-207 zeroed)
constexpr int BU_OFF  = 0;       // bf16 [128][64] linear  (B+bias)*u
constexpr int CH_OFF  = 16384;   // bf16 [128][64] swz64   C+bias -> C*H
constexpr int ROS_OFF = 0;       // bf16 [128][64] swz64   phase-3 ro tile
constexpr int DT_OFF  = 32768;   // f32 [128]
constexpr int LA_OFF  = 33280;   // f32 [64]
constexpr int LDS_BYTES = 33536; // 4 blocks/CU LDS-wise; regs bind at 2
}

typedef short bf16x8 __attribute__((ext_vector_type(8)));
typedef float f32x4  __attribute__((ext_vector_type(4)));

__device__ __forceinline__ unsigned short f2b(float f) {
    unsigned int x = __float_as_uint(f);
    return (unsigned short)((x + 0x7FFFu + ((x >> 16) & 1u)) >> 16);  // RNE
}
__device__ __forceinline__ float b2f(unsigned short h) {
    return __uint_as_float(((unsigned int)h) << 16);
}
__device__ __forceinline__ unsigned int pk2(float lo, float hi) {
    union { __hip_bfloat162 h; unsigned int u; } cv;
    cv.h = __float22bfloat162_rn(float2{lo, hi});
    return cv.u;
}
// swizzles: XOR an 8-element (16B) slot index with a row key; both give
// minimum bank depth for 16-row b128 reads AND staging writes.
__device__ __forceinline__ int swz32(int row, int col) {   // 32-col tiles
    return row * 32 + (col ^ (((row >> 1) & 3) << 3));
}
__device__ __forceinline__ int swz64(int row, int col) {   // 64-col tiles
    return row * 64 + (col ^ ((row & 7) << 3));
}
// convert 8 f32 -> bf16x8, one b128 store
__device__ __forceinline__ void cvtstore8(unsigned short* dst, float4 a, float4 b) {
    uint4 r;
    r.x = pk2(a.x, a.y); r.y = pk2(a.z, a.w);
    r.z = pk2(b.x, b.y); r.w = pk2(b.z, b.w);
    *(uint4*)dst = r;
}

__global__ __launch_bounds__(NTH, 4) void mamba_mfma(
    const float* __restrict__ X, const float* __restrict__ H0,
    const float* __restrict__ a_hat,
    const float* __restrict__ U_w, const float* __restrict__ sB_w, const float* __restrict__ sB_b,
    const float* __restrict__ sC_w, const float* __restrict__ sC_b,
    const float* __restrict__ sD1_w, const float* __restrict__ sD1_b,
    const float* __restrict__ sD2_w, const float* __restrict__ sD2_b,
    const float* __restrict__ ro_w,
    float* __restrict__ Hseq, float* __restrict__ Y, float* __restrict__ HT)
{
    __shared__ __align__(16) char smem[LDS_BYTES];
    unsigned short* XS  = (unsigned short*)(smem + XS_OFF);
    unsigned short* WS  = (unsigned short*)(smem + WS_OFF);
    unsigned short* BU  = (unsigned short*)(smem + BU_OFF);
    unsigned short* ROS = (unsigned short*)(smem + ROS_OFF);
    unsigned short* CHB = (unsigned short*)(smem + CH_OFF);
    float*          DTB = (float*)(smem + DT_OFF);
    float*          LA  = (float*)(smem + LA_OFF);

    const int tid  = threadIdx.x;
    const int lane = tid & 63;
    const int wid  = tid >> 6;     // 0..7
    const int wm   = wid >> 2;     // 0..1  (64-row t stripe)
    const int wn   = wid & 3;      // 0..3  (16-col s stripe)
    const int l15  = lane & 15;
    const int lg   = lane >> 4;    // 0..3
    const int b    = blockIdx.x >> 8;
    const int p    = blockIdx.x & 255;

    if (tid < S_N) LA[tid] = -expf(a_hat[tid]);
    // zero WS rows 200..207 (dt B-frag garbage cols read as zeros)
    if (tid < 128) ((unsigned int*)(WS + 200 * 32))[tid] = 0;

    // ---------------- Phase 1: projections, M=128(t) N=192(+8 dt) K=512 ----------------
    f32x4 acc[4][3];   // [mf][nf: 0=u 1=B 2=C for s-range wn*16..+15]
    f32x4 accdt;       // dt-feat frag: t-rows wid*16..+15, r=l15 (<8 valid)
    #pragma unroll
    for (int q = 0; q < 4; ++q) accdt[q] = 0.0f;
    #pragma unroll
    for (int mf = 0; mf < 4; ++mf)
        #pragma unroll
        for (int nf = 0; nf < 3; ++nf)
            #pragma unroll
            for (int q = 0; q < 4; ++q) acc[mf][nf][q] = 0.0f;

    // X staging: 128 rows x 4 quads of 8 f32 -> 512 units, 1/thread
    const int xr = tid >> 2, xq = tid & 3;
    const float* xsrc = X + (((size_t)b * T_N + xr) * P_N + p) * D_N + xq * 8;
    unsigned short* xdst = &XS[swz32(xr, xq * 8)];

    // W staging: interleaved row order per s-block of 16:
    //   rows g*16+w, g=0..11: triple=g%3 (0=U,1=B,2=C), s = (g/3)*16 + w
    //   rows 192..199: sD1_w
    // unit0 = rows 0..127 (1/thread), unit1 = rows 128..199 (tid<288)
    const int wr0 = tid >> 2, wq = tid & 3;
    const int wr1 = 128 + wr0;
    const bool hasW1 = (tid < 288);
    const float* wsrc0;
    {
        int g = wr0 >> 4, w = wr0 & 15, tr = g % 3, sb = g / 3;
        const float* base = (tr == 0) ? U_w : (tr == 1) ? sB_w : sC_w;
        wsrc0 = base + (size_t)(sb * 16 + w) * D_N + wq * 8;
    }
    const float* wsrc1;
    if (wr1 < 192) {
        int g = wr1 >> 4, w = wr1 & 15, tr = g % 3, sb = g / 3;
        const float* base = (tr == 0) ? U_w : (tr == 1) ? sB_w : sC_w;
        wsrc1 = base + (size_t)(sb * 16 + w) * D_N + wq * 8;
    } else if (wr1 < 200) {
        wsrc1 = sD1_w + (size_t)(wr1 - 192) * D_N + wq * 8;
    } else {
        wsrc1 = wsrc0;   // tid>=288: harmless dup load, store guarded
    }
    unsigned short* wdst0 = &WS[swz32(wr0, wq * 8)];
    unsigned short* wdst1 = &WS[swz32(wr1 < 208 ? wr1 : 0, wq * 8)];

    // prologue: chunk-0 loads
    float4 xA = *(const float4*)(xsrc),  xB = *(const float4*)(xsrc + 4);
    float4 wA0 = *(const float4*)(wsrc0), wB0 = *(const float4*)(wsrc0 + 4);
    float4 wA1 = *(const float4*)(wsrc1), wB1 = *(const float4*)(wsrc1 + 4);

    const int kb = lg * 8;
    for (int kc = 0; kc < NCH; ++kc) {
        cvtstore8(xdst, xA, xB);
        cvtstore8(wdst0, wA0, wB0);
        if (hasW1) cvtstore8(wdst1, wA1, wB1);
        __syncthreads();
        // issue next-chunk loads; latency hides under MFMA + barrier
        if (kc + 1 < NCH) {
            const float* nx = xsrc + (kc + 1) * KC;
            xA = *(const float4*)(nx); xB = *(const float4*)(nx + 4);
            const float* n0 = wsrc0 + (kc + 1) * KC;
            wA0 = *(const float4*)(n0); wB0 = *(const float4*)(n0 + 4);
            const float* n1 = wsrc1 + (kc + 1) * KC;
            wA1 = *(const float4*)(n1); wB1 = *(const float4*)(n1 + 4);
        }
        bf16x8 a[4];
        #pragma unroll
        for (int mf = 0; mf < 4; ++mf)
            a[mf] = *(const bf16x8*)&XS[swz32(wm * 64 + mf * 16 + l15, kb)];
        #pragma unroll
        for (int nf = 0; nf < 3; ++nf) {
            bf16x8 bb = *(const bf16x8*)&WS[swz32(wn * 48 + nf * 16 + l15, kb)];
            #pragma unroll
            for (int mf = 0; mf < 4; ++mf)
                acc[mf][nf] = __builtin_amdgcn_mfma_f32_16x16x32_bf16(a[mf], bb, acc[mf][nf], 0, 0, 0);
        }
        {   // dt frag: this wave's 16 t-rows (static re-read avoids runtime a[] index)
            bf16x8 adt = *(const bf16x8*)&XS[swz32(wid * 16 + l15, kb)];
            bf16x8 bd  = *(const bf16x8*)&WS[swz32(192 + l15, kb)];
            accdt = __builtin_amdgcn_mfma_f32_16x16x32_bf16(adt, bd, accdt, 0, 0, 0);
        }
        __syncthreads();
    }

    // ---------------- Phase 1 epilogue ----------------
    // C/D frag: col=lane&15, row=(lane>>4)*4+reg (m89-verified)
    {
        const int s = wn * 16 + l15;
        const float biasB = sB_b[s], biasC = sC_b[s];
        #pragma unroll
        for (int mf = 0; mf < 4; ++mf) {
            #pragma unroll
            for (int q = 0; q < 4; ++q) {
                const int t = wm * 64 + mf * 16 + lg * 4 + q;
                const float u  = acc[mf][0][q];
                const float Bv = acc[mf][1][q] + biasB;
                const float Cv = acc[mf][2][q] + biasC;
                BU[t * 64 + s]   = f2b(Bv * u);    // reference: B_t * u (one rounding)
                CHB[swz64(t, s)] = f2b(Cv);
            }
        }
    }
    {   // dt reduce: this wave owns t-rows wid*16..+15
        const float w2 = (l15 < 8) ? sD2_w[l15] : 0.0f;
        const float b1 = (l15 < 8) ? sD1_b[l15] : 0.0f;
        const float b2 = sD2_b[0];
        #pragma unroll
        for (int q = 0; q < 4; ++q) {
            float z = accdt[q] + b1;
            float w = (z / (1.0f + expf(-z))) * w2;   // silu * sD2_w
            w = (l15 < 8) ? w : 0.0f;
            w += __shfl_xor(w, 1);
            w += __shfl_xor(w, 2);
            w += __shfl_xor(w, 4);
            if (l15 == 0) {
                float zz = w + b2;
                DTB[wid * 16 + lg * 4 + q] = (zz > 20.0f) ? zz : log1pf(expf(zz));
            }
        }
    }
    __syncthreads();

    // issue phase-3 pass-0 ro loads now: HBM/L2 latency hides under the scan
    const int rrow = tid >> 2, rq = tid & 3;
    const float* rosrc = ro_w + (size_t)rrow * S_N + rq * 16;
    float4 r0a = *(const float4*)(rosrc);
    float4 r0b = *(const float4*)(rosrc + 4);
    float4 r0c = *(const float4*)(rosrc + 8);
    float4 r0d = *(const float4*)(rosrc + 12);

    // ---------------- Phase 2: sequential scan (reference clamp semantics, fp32) ----------------
    if (tid < 64) {
        const int s = tid;
        const float la = LA[s];
        const float h0 = H0[((size_t)b * P_N + p) * S_N + s];
        float Pcv = 1.0f, cv = 0.0f, Hv = 0.0f;
        float* hout = Hseq + ((size_t)b * T_N * P_N + p) * S_N + s;
        for (int t = 0; t < T_N; ++t) {
            const float Av = expf(DTB[t] * la);
            const float bv = (1.0f - Av) * b2f(BU[t * 64 + s]);
            Pcv *= fmaxf(Av, 1e-12f);                 // Pc = cumprod(max(A,eps))
            cv += bv * (1.0f / fmaxf(Pcv, 1e-12f));   // c += b * invP
            Hv = Pcv * (h0 + cv);
            hout[(size_t)t * P_N * S_N] = Hv;
            const int e = swz64(t, s);
            CHB[e] = f2b(b2f(CHB[e]) * Hv);           // CH = C * H
        }
        HT[((size_t)b * P_N + p) * S_N + s] = Hv;
    }
    __syncthreads();

    // ---------------- Phase 3: Y = CH(128x64) x ro^T(64x512), 4 passes of 128 cols ----------------
    // hoist CH A-frags once (CHB final after scan; acc regs dead)
    bf16x8 af0[4], af1[4];
    #pragma unroll
    for (int mf = 0; mf < 4; ++mf) {
        af0[mf] = *(const bf16x8*)&CHB[swz64(wm * 64 + mf * 16 + l15, lg * 8)];
        af1[mf] = *(const bf16x8*)&CHB[swz64(wm * 64 + mf * 16 + l15, 32 + lg * 8)];
    }
    // write pass-0 ro tile
    cvtstore8(&ROS[swz64(rrow, rq * 16)],     r0a, r0b);
    cvtstore8(&ROS[swz64(rrow, rq * 16 + 8)], r0c, r0d);
    __syncthreads();

    for (int pp = 0; pp < 4; ++pp) {
        if (pp < 3) {   // prefetch next ro pass during this pass's MFMA
            const float* ns = ro_w + (size_t)((pp + 1) * 128 + rrow) * S_N + rq * 16;
            r0a = *(const float4*)(ns);
            r0b = *(const float4*)(ns + 4);
            r0c = *(const float4*)(ns + 8);
            r0d = *(const float4*)(ns + 12);
        }
        f32x4 yacc[4][2];
        #pragma unroll
        for (int mf = 0; mf < 4; ++mf)
            #pragma unroll
            for (int nf = 0; nf < 2; ++nf)
                #pragma unroll
                for (int q = 0; q < 4; ++q) yacc[mf][nf][q] = 0.0f;
        #pragma unroll
        for (int nf = 0; nf < 2; ++nf) {
            bf16x8 bb0 = *(const bf16x8*)&ROS[swz64(wn * 32 + nf * 16 + l15, lg * 8)];
            bf16x8 bb1 = *(const bf16x8*)&ROS[swz64(wn * 32 + nf * 16 + l15, 32 + lg * 8)];
            #pragma unroll
            for (int mf = 0; mf < 4; ++mf) {
                yacc[mf][nf] = __builtin_amdgcn_mfma_f32_16x16x32_bf16(af0[mf], bb0, yacc[mf][nf], 0, 0, 0);
                yacc[mf][nf] = __builtin_amdgcn_mfma_f32_16x16x32_bf16(af1[mf], bb1, yacc[mf][nf], 0, 0, 0);
            }
        }
        #pragma unroll
        for (int mf = 0; mf < 4; ++mf) {
            const int t0 = wm * 64 + mf * 16 + lg * 4;
            float* ybase = Y + (((size_t)b * T_N + t0) * P_N + p) * D_N + pp * 128 + wn * 32 + l15;
            #pragma unroll
            for (int nf = 0; nf < 2; ++nf) {
                #pragma unroll
                for (int q = 0; q < 4; ++q)
                    ybase[(size_t)q * P_N * D_N + nf * 16] = yacc[mf][nf][q];
            }
        }
        __syncthreads();   // all reads of ROS done
        if (pp < 3) {
            cvtstore8(&ROS[swz64(rrow, rq * 16)],     r0a, r0b);
            cvtstore8(&ROS[swz64(rrow, rq * 16 + 8)], r0c, r0d);
            __syncthreads();
        }
    }
}

extern "C" void kernel_launch(void* const* d_in, const int* in_sizes, int n_in,
                              void* d_out, int out_size, void* d_ws, size_t ws_size,
                              hipStream_t stream) {
    const float* X     = (const float*)d_in[0];
    const float* H0    = (const float*)d_in[1];
    const float* a_hat = (const float*)d_in[2];
    const float* U_w   = (const float*)d_in[3];
    const float* sB_w  = (const float*)d_in[4];
    const float* sB_b  = (const float*)d_in[5];
    const float* sC_w  = (const float*)d_in[6];
    const float* sC_b  = (const float*)d_in[7];
    const float* sD1_w = (const float*)d_in[8];
    const float* sD1_b = (const float*)d_in[9];
    const float* sD2_w = (const float*)d_in[10];
    const float* sD2_b = (const float*)d_in[11];
    const float* ro_w  = (const float*)d_in[12];

    float* out   = (float*)d_out;
    float* HseqP = out;
    float* YP    = out + (size_t)B_N * T_N * P_N * S_N;
    float* HTP   = YP  + (size_t)B_N * T_N * P_N * D_N;

    hipLaunchKernelGGL(mamba_mfma, dim3(B_N * P_N), dim3(NTH), 0, stream,
                       X, H0, a_hat, U_w, sB_w, sB_b, sC_w, sC_b,
                       sD1_w, sD1_b, sD2_w, sD2_b, ro_w, HseqP, YP, HTP);
}

// Round 7
// 156.475 us; speedup vs baseline: 2.7096x; 1.0201x over previous
//
#include <hip/hip_runtime.h>
#include <hip/hip_bf16.h>
#include <math.h>

namespace {
constexpr int B_N = 4, T_N = 128, P_N = 256, D_N = 512, S_N = 64;
constexpr int NTH = 512;
constexpr int KC  = 32;
constexpr int NCH = D_N / KC;   // 16 k-chunks

// LDS layout (bytes). Liveness (barrier-protected):
//   phase1 k-loop : XS0 [0,8192) WS0 [8192,21504) XS1 [21504,29696) WS1 [29696,43008)
//   epilogue+scan : BU [0,16384) + CHB [16384,32768)
//   phase3        : ROS [0,16384) (BU dead) + CHB
constexpr int XS0_OFF = 0;       // bf16 [128][32] swz32
constexpr int WS0_OFF = 8192;    // bf16 [208][32] swz32 (rows 200-207 zeroed)
constexpr int XS1_OFF = 21504;
constexpr int WS1_OFF = 29696;
constexpr int BU_OFF  = 0;       // bf16 [128][64] linear  (B+bias)*u
constexpr int CH_OFF  = 16384;   // bf16 [128][64] swz64   C+bias -> C*H
constexpr int ROS_OFF = 0;       // bf16 [128][64] swz64   phase-3 ro tile
constexpr int DT_OFF  = 43008;   // f32 [128]
constexpr int LDS_BYTES = 43520; // 2 blocks/CU (87 KB); regs bind at 2 anyway
}

typedef short bf16x8 __attribute__((ext_vector_type(8)));
typedef float f32x4  __attribute__((ext_vector_type(4)));

__device__ __forceinline__ unsigned short f2b(float f) {
    unsigned int x = __float_as_uint(f);
    return (unsigned short)((x + 0x7FFFu + ((x >> 16) & 1u)) >> 16);  // RNE
}
__device__ __forceinline__ float b2f(unsigned short h) {
    return __uint_as_float(((unsigned int)h) << 16);
}
__device__ __forceinline__ unsigned int pk2(float lo, float hi) {
    union { __hip_bfloat162 h; unsigned int u; } cv;
    cv.h = __float22bfloat162_rn(float2{lo, hi});
    return cv.u;
}
// swizzles: XOR an 8-element (16B) slot index with a row key.
__device__ __forceinline__ int swz32(int row, int col) {   // 32-col tiles
    return row * 32 + (col ^ (((row >> 1) & 3) << 3));
}
__device__ __forceinline__ int swz64(int row, int col) {   // 64-col tiles
    return row * 64 + (col ^ ((row & 7) << 3));
}
// convert 8 f32 -> bf16x8, one b128 store
__device__ __forceinline__ void cvtstore8(unsigned short* dst, float4 a, float4 b) {
    uint4 r;
    r.x = pk2(a.x, a.y); r.y = pk2(a.z, a.w);
    r.z = pk2(b.x, b.y); r.w = pk2(b.z, b.w);
    *(uint4*)dst = r;
}

__global__ __launch_bounds__(NTH, 4) void mamba_mfma(
    const float* __restrict__ X, const float* __restrict__ H0,
    const float* __restrict__ a_hat,
    const float* __restrict__ U_w, const float* __restrict__ sB_w, const float* __restrict__ sB_b,
    const float* __restrict__ sC_w, const float* __restrict__ sC_b,
    const float* __restrict__ sD1_w, const float* __restrict__ sD1_b,
    const float* __restrict__ sD2_w, const float* __restrict__ sD2_b,
    const float* __restrict__ ro_w,
    float* __restrict__ Hseq, float* __restrict__ Y, float* __restrict__ HT)
{
    __shared__ __align__(16) char smem[LDS_BYTES];
    unsigned short* XS0 = (unsigned short*)(smem + XS0_OFF);
    unsigned short* WS0 = (unsigned short*)(smem + WS0_OFF);
    unsigned short* XS1 = (unsigned short*)(smem + XS1_OFF);
    unsigned short* WS1 = (unsigned short*)(smem + WS1_OFF);
    unsigned short* BU  = (unsigned short*)(smem + BU_OFF);
    unsigned short* ROS = (unsigned short*)(smem + ROS_OFF);
    unsigned short* CHB = (unsigned short*)(smem + CH_OFF);
    float*          DTB = (float*)(smem + DT_OFF);

    const int tid  = threadIdx.x;
    const int lane = tid & 63;
    const int wid  = tid >> 6;     // 0..7
    const int wm   = wid >> 2;     // 0..1  (64-row t stripe)
    const int wn   = wid & 3;      // 0..3  (16-col s stripe)
    const int l15  = lane & 15;
    const int lg   = lane >> 4;    // 0..3
    const int b    = blockIdx.x >> 8;
    const int p    = blockIdx.x & 255;

    // scan-wave constants hoisted to regs (issued early; hide under phase 1)
    const float la  = (tid < 64) ? -expf(a_hat[tid]) : 0.0f;
    const float h0v = (tid < 64) ? H0[((size_t)b * P_N + p) * S_N + tid] : 0.0f;

    // zero WS rows 200..207 in BOTH buffers (dt B-frag garbage cols read as zeros)
    if (tid < 128) {
        ((unsigned int*)(WS0 + 200 * 32))[tid] = 0;
        ((unsigned int*)(WS1 + 200 * 32))[tid] = 0;
    }

    // ---------------- Phase 1: projections, M=128(t) N=192(+8 dt) K=512 ----------------
    f32x4 acc[4][3];   // [mf][nf: 0=u 1=B 2=C for s-range wn*16..+15]
    f32x4 accdt;       // dt-feat frag: t-rows wid*16..+15, r=l15 (<8 valid)
    #pragma unroll
    for (int q = 0; q < 4; ++q) accdt[q] = 0.0f;
    #pragma unroll
    for (int mf = 0; mf < 4; ++mf)
        #pragma unroll
        for (int nf = 0; nf < 3; ++nf)
            #pragma unroll
            for (int q = 0; q < 4; ++q) acc[mf][nf][q] = 0.0f;

    // X staging: 128 rows x 4 quads of 8 f32 -> 512 units, 1/thread
    const int xr = tid >> 2, xq = tid & 3;
    const float* xsrc = X + (((size_t)b * T_N + xr) * P_N + p) * D_N + xq * 8;
    const int xoff = swz32(xr, xq * 8);

    // W staging: interleaved row order per s-block of 16:
    //   rows g*16+w, g=0..11: triple=g%3 (0=U,1=B,2=C), s = (g/3)*16 + w
    //   rows 192..199: sD1_w
    const int wr0 = tid >> 2, wq = tid & 3;
    const int wr1 = 128 + wr0;
    const bool hasW1 = (tid < 288);
    const float* wsrc0;
    {
        int g = wr0 >> 4, w = wr0 & 15, tr = g % 3, sb = g / 3;
        const float* base = (tr == 0) ? U_w : (tr == 1) ? sB_w : sC_w;
        wsrc0 = base + (size_t)(sb * 16 + w) * D_N + wq * 8;
    }
    const float* wsrc1;
    if (wr1 < 192) {
        int g = wr1 >> 4, w = wr1 & 15, tr = g % 3, sb = g / 3;
        const float* base = (tr == 0) ? U_w : (tr == 1) ? sB_w : sC_w;
        wsrc1 = base + (size_t)(sb * 16 + w) * D_N + wq * 8;
    } else if (wr1 < 200) {
        wsrc1 = sD1_w + (size_t)(wr1 - 192) * D_N + wq * 8;
    } else {
        wsrc1 = wsrc0;   // tid>=288: harmless dup load, store guarded
    }
    const int woff0 = swz32(wr0, wq * 8);
    const int woff1 = swz32(wr1 < 208 ? wr1 : 0, wq * 8);

    // prologue: load+stage chunk 0 into buf0, then issue chunk-1 loads
    float4 xA = *(const float4*)(xsrc),   xB = *(const float4*)(xsrc + 4);
    float4 wA0 = *(const float4*)(wsrc0), wB0 = *(const float4*)(wsrc0 + 4);
    float4 wA1 = *(const float4*)(wsrc1), wB1 = *(const float4*)(wsrc1 + 4);
    cvtstore8(&XS0[xoff],  xA, xB);
    cvtstore8(&WS0[woff0], wA0, wB0);
    if (hasW1) cvtstore8(&WS0[woff1], wA1, wB1);
    {
        const float* nx = xsrc + KC;
        xA = *(const float4*)(nx); xB = *(const float4*)(nx + 4);
        const float* n0 = wsrc0 + KC;
        wA0 = *(const float4*)(n0); wB0 = *(const float4*)(n0 + 4);
        const float* n1 = wsrc1 + KC;
        wA1 = *(const float4*)(n1); wB1 = *(const float4*)(n1 + 4);
    }
    __syncthreads();

    const int kb = lg * 8;
    #pragma unroll 2
    for (int kc = 0; kc < NCH; ++kc) {
        unsigned short* XSc = (kc & 1) ? XS1 : XS0;
        unsigned short* WSc = (kc & 1) ? WS1 : WS0;
        unsigned short* XSn = (kc & 1) ? XS0 : XS1;
        unsigned short* WSn = (kc & 1) ? WS0 : WS1;
        // write chunk kc+1 into alternate buffer (vmcnt stall covered by other waves)
        if (kc + 1 < NCH) {
            cvtstore8(&XSn[xoff],  xA, xB);
            cvtstore8(&WSn[woff0], wA0, wB0);
            if (hasW1) cvtstore8(&WSn[woff1], wA1, wB1);
        }
        // issue chunk kc+2 loads (latency hides under MFMA + barrier + next write-stall)
        if (kc + 2 < NCH) {
            const float* nx = xsrc + (kc + 2) * KC;
            xA = *(const float4*)(nx); xB = *(const float4*)(nx + 4);
            const float* n0 = wsrc0 + (kc + 2) * KC;
            wA0 = *(const float4*)(n0); wB0 = *(const float4*)(n0 + 4);
            const float* n1 = wsrc1 + (kc + 2) * KC;
            wA1 = *(const float4*)(n1); wB1 = *(const float4*)(n1 + 4);
        }
        __builtin_amdgcn_s_setprio(1);
        bf16x8 a[4];
        #pragma unroll
        for (int mf = 0; mf < 4; ++mf)
            a[mf] = *(const bf16x8*)&XSc[swz32(wm * 64 + mf * 16 + l15, kb)];
        #pragma unroll
        for (int nf = 0; nf < 3; ++nf) {
            bf16x8 bb = *(const bf16x8*)&WSc[swz32(wn * 48 + nf * 16 + l15, kb)];
            #pragma unroll
            for (int mf = 0; mf < 4; ++mf)
                acc[mf][nf] = __builtin_amdgcn_mfma_f32_16x16x32_bf16(a[mf], bb, acc[mf][nf], 0, 0, 0);
        }
        {   // dt frag: this wave's 16 t-rows
            bf16x8 adt = *(const bf16x8*)&XSc[swz32(wid * 16 + l15, kb)];
            bf16x8 bd  = *(const bf16x8*)&WSc[swz32(192 + l15, kb)];
            accdt = __builtin_amdgcn_mfma_f32_16x16x32_bf16(adt, bd, accdt, 0, 0, 0);
        }
        __builtin_amdgcn_s_setprio(0);
        __syncthreads();   // single barrier per chunk
    }

    // ---------------- Phase 1 epilogue ----------------
    // C/D frag: col=lane&15, row=(lane>>4)*4+reg (m89-verified)
    {
        const int s = wn * 16 + l15;
        const float biasB = sB_b[s], biasC = sC_b[s];
        #pragma unroll
        for (int mf = 0; mf < 4; ++mf) {
            #pragma unroll
            for (int q = 0; q < 4; ++q) {
                const int t = wm * 64 + mf * 16 + lg * 4 + q;
                const float u  = acc[mf][0][q];
                const float Bv = acc[mf][1][q] + biasB;
                const float Cv = acc[mf][2][q] + biasC;
                BU[t * 64 + s]   = f2b(Bv * u);    // reference: B_t * u (one rounding)
                CHB[swz64(t, s)] = f2b(Cv);
            }
        }
    }
    {   // dt reduce: this wave owns t-rows wid*16..+15
        const float w2 = (l15 < 8) ? sD2_w[l15] : 0.0f;
        const float b1 = (l15 < 8) ? sD1_b[l15] : 0.0f;
        const float b2 = sD2_b[0];
        #pragma unroll
        for (int q = 0; q < 4; ++q) {
            float z = accdt[q] + b1;
            float w = (z / (1.0f + expf(-z))) * w2;   // silu * sD2_w
            w = (l15 < 8) ? w : 0.0f;
            w += __shfl_xor(w, 1);
            w += __shfl_xor(w, 2);
            w += __shfl_xor(w, 4);
            if (l15 == 0) {
                float zz = w + b2;
                DTB[wid * 16 + lg * 4 + q] = (zz > 20.0f) ? zz : log1pf(expf(zz));
            }
        }
    }
    __syncthreads();

    // issue phase-3 pass-0 ro loads now: latency hides under the scan
    const int rrow = tid >> 2, rq = tid & 3;
    const float* rosrc = ro_w + (size_t)rrow * S_N + rq * 16;
    float4 r0a = *(const float4*)(rosrc);
    float4 r0b = *(const float4*)(rosrc + 4);
    float4 r0c = *(const float4*)(rosrc + 8);
    float4 r0d = *(const float4*)(rosrc + 12);

    // ---------------- Phase 2: sequential scan (reference clamp semantics, fp32) ----------------
    if (tid < 64) {
        const int s = tid;
        float Pcv = 1.0f, cv = 0.0f, Hv = 0.0f;
        float* hout = Hseq + ((size_t)b * T_N * P_N + p) * S_N + s;
        for (int t = 0; t < T_N; ++t) {
            const float Av = expf(DTB[t] * la);
            const float bv = (1.0f - Av) * b2f(BU[t * 64 + s]);
            Pcv *= fmaxf(Av, 1e-12f);                 // Pc = cumprod(max(A,eps))
            cv += bv * (1.0f / fmaxf(Pcv, 1e-12f));   // c += b * invP
            Hv = Pcv * (h0v + cv);
            hout[(size_t)t * P_N * S_N] = Hv;
            const int e = swz64(t, s);
            CHB[e] = f2b(b2f(CHB[e]) * Hv);           // CH = C * H
        }
        HT[((size_t)b * P_N + p) * S_N + s] = Hv;
    }
    __syncthreads();

    // ---------------- Phase 3: Y = CH(128x64) x ro^T(64x512), 4 passes of 128 cols ----------------
    // hoist CH A-frags once (CHB final after scan; acc regs dead)
    bf16x8 af0[4], af1[4];
    #pragma unroll
    for (int mf = 0; mf < 4; ++mf) {
        af0[mf] = *(const bf16x8*)&CHB[swz64(wm * 64 + mf * 16 + l15, lg * 8)];
        af1[mf] = *(const bf16x8*)&CHB[swz64(wm * 64 + mf * 16 + l15, 32 + lg * 8)];
    }
    // write pass-0 ro tile
    cvtstore8(&ROS[swz64(rrow, rq * 16)],     r0a, r0b);
    cvtstore8(&ROS[swz64(rrow, rq * 16 + 8)], r0c, r0d);
    __syncthreads();

    for (int pp = 0; pp < 4; ++pp) {
        if (pp < 3) {   // prefetch next ro pass during this pass's MFMA
            const float* ns = ro_w + (size_t)((pp + 1) * 128 + rrow) * S_N + rq * 16;
            r0a = *(const float4*)(ns);
            r0b = *(const float4*)(ns + 4);
            r0c = *(const float4*)(ns + 8);
            r0d = *(const float4*)(ns + 12);
        }
        f32x4 yacc[4][2];
        #pragma unroll
        for (int mf = 0; mf < 4; ++mf)
            #pragma unroll
            for (int nf = 0; nf < 2; ++nf)
                #pragma unroll
                for (int q = 0; q < 4; ++q) yacc[mf][nf][q] = 0.0f;
        #pragma unroll
        for (int nf = 0; nf < 2; ++nf) {
            bf16x8 bb0 = *(const bf16x8*)&ROS[swz64(wn * 32 + nf * 16 + l15, lg * 8)];
            bf16x8 bb1 = *(const bf16x8*)&ROS[swz64(wn * 32 + nf * 16 + l15, 32 + lg * 8)];
            #pragma unroll
            for (int mf = 0; mf < 4; ++mf) {
                yacc[mf][nf] = __builtin_amdgcn_mfma_f32_16x16x32_bf16(af0[mf], bb0, yacc[mf][nf], 0, 0, 0);
                yacc[mf][nf] = __builtin_amdgcn_mfma_f32_16x16x32_bf16(af1[mf], bb1, yacc[mf][nf], 0, 0, 0);
            }
        }
        #pragma unroll
        for (int mf = 0; mf < 4; ++mf) {
            const int t0 = wm * 64 + mf * 16 + lg * 4;
            float* ybase = Y + (((size_t)b * T_N + t0) * P_N + p) * D_N + pp * 128 + wn * 32 + l15;
            #pragma unroll
            for (int nf = 0; nf < 2; ++nf) {
                #pragma unroll
                for (int q = 0; q < 4; ++q)
                    ybase[(size_t)q * P_N * D_N + nf * 16] = yacc[mf][nf][q];
            }
        }
        __syncthreads();   // all reads of ROS done
        if (pp < 3) {
            cvtstore8(&ROS[swz64(rrow, rq * 16)],     r0a, r0b);
            cvtstore8(&ROS[swz64(rrow, rq * 16 + 8)], r0c, r0d);
            __syncthreads();
        }
    }
}

extern "C" void kernel_launch(void* const* d_in, const int* in_sizes, int n_in,
                              void* d_out, int out_size, void* d_ws, size_t ws_size,
                              hipStream_t stream) {
    const float* X     = (const float*)d_in[0];
    const float* H0    = (const float*)d_in[1];
    const float* a_hat = (const float*)d_in[2];
    const float* U_w   = (const float*)d_in[3];
    const float* sB_w  = (const float*)d_in[4];
    const float* sB_b  = (const float*)d_in[5];
    const float* sC_w  = (const float*)d_in[6];
    const float* sC_b  = (const float*)d_in[7];
    const float* sD1_w = (const float*)d_in[8];
    const float* sD1_b = (const float*)d_in[9];
    const float* sD2_w = (const float*)d_in[10];
    const float* sD2_b = (const float*)d_in[11];
    const float* ro_w  = (const float*)d_in[12];

    float* out   = (float*)d_out;
    float* HseqP = out;
    float* YP    = out + (size_t)B_N * T_N * P_N * S_N;
    float* HTP   = YP  + (size_t)B_N * T_N * P_N * D_N;

    hipLaunchKernelGGL(mamba_mfma, dim3(B_N * P_N), dim3(NTH), 0, stream,
                       X, H0, a_hat, U_w, sB_w, sB_b, sC_w, sC_b,
                       sD1_w, sD1_b, sD2_w, sD2_b, ro_w, HseqP, YP, HTP);
}